// Round 1
// baseline (3579.361 us; speedup 1.0000x reference)
//
#include <hip/hip_runtime.h>
#include <hip/hip_bf16.h>

#define D 48
#define GNUM 64
#define HDIM 128
#define ODIM 12
#define BN_EPS 1e-5f

// ---------------- setup kernels ----------------

__global__ __launch_bounds__(256) void k_deg(const int* __restrict__ row, int* __restrict__ deg, int E) {
    int e = blockIdx.x * 256 + threadIdx.x;
    if (e < E) atomicAdd(&deg[row[e]], 1);
}

__global__ __launch_bounds__(256) void k_dinv(const int* __restrict__ deg, float* __restrict__ dinv, int N) {
    int i = blockIdx.x * 256 + threadIdx.x;
    if (i < N) dinv[i] = deg[i] > 0 ? rsqrtf((float)deg[i]) : 0.f;
}

__global__ __launch_bounds__(256) void k_scan1(const int* __restrict__ deg, int* __restrict__ incl,
                                               int* __restrict__ bsum, int N) {
    __shared__ int s[256];
    int i = blockIdx.x * 256 + threadIdx.x;
    s[threadIdx.x] = (i < N) ? deg[i] : 0;
    __syncthreads();
    for (int off = 1; off < 256; off <<= 1) {
        int t = (threadIdx.x >= off) ? s[threadIdx.x - off] : 0;
        __syncthreads();
        s[threadIdx.x] += t;
        __syncthreads();
    }
    if (i < N) incl[i] = s[threadIdx.x];
    if (threadIdx.x == 255) bsum[blockIdx.x] = s[255];
}

__global__ __launch_bounds__(512) void k_scan2(int* __restrict__ bsum, int nb) {
    __shared__ int s[512];
    int t = threadIdx.x;
    s[t] = (t < nb) ? bsum[t] : 0;
    __syncthreads();
    for (int off = 1; off < 512; off <<= 1) {
        int v = (t >= off) ? s[t - off] : 0;
        __syncthreads();
        s[t] += v;
        __syncthreads();
    }
    if (t < nb) bsum[t] = s[t];
}

__global__ __launch_bounds__(256) void k_scan3(const int* __restrict__ incl, const int* __restrict__ bsum,
                                               int* __restrict__ rowptr, int N) {
    int i = blockIdx.x * 256 + threadIdx.x;
    if (i < N) {
        int add = (blockIdx.x > 0) ? bsum[blockIdx.x - 1] : 0;
        rowptr[i + 1] = incl[i] + add;
    }
    if (i == 0) rowptr[0] = 0;
}

__global__ __launch_bounds__(256) void k_fill(const int* __restrict__ row, const int* __restrict__ col,
                                              const int* __restrict__ rowptr, int* __restrict__ fillc,
                                              const float* __restrict__ dinv, int* __restrict__ ecol,
                                              float* __restrict__ ednv, int E) {
    int e = blockIdx.x * 256 + threadIdx.x;
    if (e < E) {
        int r = row[e], c = col[e];
        int p = rowptr[r] + atomicAdd(&fillc[r], 1);
        ecol[p] = c;
        ednv[p] = dinv[c];
    }
}

// ---------------- per-step kernels ----------------

// Tx1 = lhat(cur): wave per node, lanes 0..47 = features
__global__ __launch_bounds__(256) void k_lhat(const float* __restrict__ cur, const int* __restrict__ rowptr,
                                              const int* __restrict__ ecol, const float* __restrict__ ednv,
                                              const float* __restrict__ dinv, float* __restrict__ tx1, int N) {
    int lane = threadIdx.x & 63;
    int i = (blockIdx.x * 256 + threadIdx.x) >> 6;
    if (i >= N) return;
    int s = rowptr[i], e = rowptr[i + 1];
    if (lane < D) {
        float acc = 0.f;
        for (int p = s; p < e; ++p) {
            int c = ecol[p];
            float w = ednv[p];
            acc += w * cur[c * D + lane];
        }
        tx1[i * D + lane] = -dinv[i] * acc;
    }
}

// Tx2 = 2*lhat(Tx1) - Tx0; t = relu(Tx0@W0 + Tx1@W1 + Tx2@W2 + b); BN stat partials
__global__ __launch_bounds__(256) void k_cheb(const float* __restrict__ tx0buf, const float* __restrict__ tx1buf,
                                              const int* __restrict__ rowptr, const int* __restrict__ ecol,
                                              const float* __restrict__ ednv, const float* __restrict__ dinv,
                                              const float* __restrict__ W, const float* __restrict__ b,
                                              float* __restrict__ tbuf, float* __restrict__ bnstats, int N) {
    __shared__ float WL[3 * D * D];
    __shared__ float bL[D];
    __shared__ float red[2 * D];
    for (int t = threadIdx.x; t < 3 * D * D; t += 256) WL[t] = W[t];
    if (threadIdx.x < D) bL[threadIdx.x] = b[threadIdx.x];
    if (threadIdx.x < 2 * D) red[threadIdx.x] = 0.f;
    __syncthreads();

    int lane = threadIdx.x & 63;
    int wid = (blockIdx.x * 256 + threadIdx.x) >> 6;
    int nw = (gridDim.x * 256) >> 6;
    float psum = 0.f, psumsq = 0.f;

    for (int i = wid; i < N; i += nw) {
        int s = rowptr[i], e = rowptr[i + 1];
        float t0 = 0.f, t1v = 0.f, acc = 0.f;
        if (lane < D) {
            t0 = tx0buf[i * D + lane];
            t1v = tx1buf[i * D + lane];
            for (int p = s; p < e; ++p) {
                int c = ecol[p];
                float w = ednv[p];
                acc += w * tx1buf[c * D + lane];
            }
        }
        float t2v = -2.f * dinv[i] * acc - t0;

        float o = (lane < D) ? bL[lane] : 0.f;
        for (int k = 0; k < D; ++k) {
            float a0 = __shfl(t0, k, 64);
            float a1 = __shfl(t1v, k, 64);
            float a2 = __shfl(t2v, k, 64);
            if (lane < D) {
                o += a0 * WL[k * D + lane] + a1 * WL[D * D + k * D + lane] + a2 * WL[2 * D * D + k * D + lane];
            }
        }
        o = fmaxf(o, 0.f);
        if (lane < D) {
            tbuf[i * D + lane] = o;
            psum += o;
            psumsq += o * o;
        }
    }
    if (lane < D) {
        atomicAdd(&red[lane], psum);
        atomicAdd(&red[D + lane], psumsq);
    }
    __syncthreads();
    if (threadIdx.x < 2 * D) atomicAdd(&bnstats[threadIdx.x], red[threadIdx.x]);
}

__global__ __launch_bounds__(64) void k_bnfin(float* __restrict__ bnstats, const float* __restrict__ gamma,
                                              const float* __restrict__ beta, float* __restrict__ ss, float Ninv) {
    int t = threadIdx.x;
    if (t < D) {
        float mean = bnstats[t] * Ninv;
        float var = bnstats[D + t] * Ninv - mean * mean;
        var = fmaxf(var, 0.f);
        float sc = gamma[t] * rsqrtf(var + BN_EPS);
        ss[t] = sc;
        ss[D + t] = beta[t] - mean * sc;
        bnstats[t] = 0.f;
        bnstats[D + t] = 0.f;
    }
}

// out[i] = deg>0 ? BN(max over neighbors of t) : 0   (min tracked for scale<0 generality)
__global__ __launch_bounds__(256) void k_pool(const float* __restrict__ tbuf, const int* __restrict__ rowptr,
                                              const int* __restrict__ ecol, const float* __restrict__ ss,
                                              float* __restrict__ outbuf, int N) {
    int lane = threadIdx.x & 63;
    int i = (blockIdx.x * 256 + threadIdx.x) >> 6;
    if (i >= N) return;
    int s = rowptr[i], e = rowptr[i + 1];
    if (lane < D) {
        float val;
        if (s == e) {
            val = 0.f;
        } else {
            float mx = -3.4e38f, mn = 3.4e38f;
            for (int p = s; p < e; ++p) {
                int c = ecol[p];
                float v = tbuf[c * D + lane];
                mx = fmaxf(mx, v);
                mn = fminf(mn, v);
            }
            float sc = ss[lane], sh = ss[D + lane];
            val = (sc >= 0.f) ? sc * mx + sh : sc * mn + sh;
        }
        outbuf[i * D + lane] = val;
    }
}

// ---------------- final pooling + MLP ----------------

__global__ __launch_bounds__(256) void k_gpool(const float* __restrict__ outbuf, const int* __restrict__ batch,
                                               float* __restrict__ g, int N, int chunk) {
    int lane = threadIdx.x & 63;
    int wid = (blockIdx.x * 256 + threadIdx.x) >> 6;
    int start = wid * chunk;
    if (start >= N) return;
    int end = start + chunk;
    if (end > N) end = N;
    int curb = batch[start];
    float acc = 0.f;
    for (int i = start; i < end; ++i) {
        int bi = batch[i];
        if (bi != curb) {
            if (lane < D) atomicAdd(&g[curb * D + lane], acc);
            curb = bi;
            acc = 0.f;
        }
        if (lane < D) acc += outbuf[i * D + lane];
    }
    if (lane < D) atomicAdd(&g[curb * D + lane], acc);
}

__global__ __launch_bounds__(256) void k_mlp(const float* __restrict__ g, const float* __restrict__ W1,
                                             const float* __restrict__ b1, const float* __restrict__ W2,
                                             const float* __restrict__ b2, float* __restrict__ out) {
    __shared__ float gL[GNUM * D];      // 12 KB
    __shared__ float hL[GNUM * HDIM];   // 32 KB
    __shared__ float W1L[D * HDIM];     // 24 KB
    int t = threadIdx.x;
    for (int i = t; i < GNUM * D; i += 256) gL[i] = g[i];
    for (int i = t; i < D * HDIM; i += 256) W1L[i] = W1[i];
    __syncthreads();
    for (int i = t; i < GNUM * HDIM; i += 256) {
        int gi = i >> 7, hj = i & 127;
        float a = b1[hj];
        for (int k = 0; k < D; ++k) a += gL[gi * D + k] * W1L[k * HDIM + hj];
        hL[i] = fmaxf(a, 0.f);
    }
    __syncthreads();
    for (int i = t; i < GNUM * ODIM; i += 256) {
        int gi = i / ODIM, oj = i % ODIM;
        float a = b2[oj];
        for (int k = 0; k < HDIM; ++k) a += hL[gi * HDIM + k] * W2[k * ODIM + oj];
        out[i] = a;
    }
}

// ---------------- launch ----------------

extern "C" void kernel_launch(void* const* d_in, const int* in_sizes, int n_in,
                              void* d_out, int out_size, void* d_ws, size_t ws_size,
                              hipStream_t stream) {
    const float* x     = (const float*)d_in[0];
    const int*   ei    = (const int*)d_in[1];
    const int*   batch = (const int*)d_in[2];
    // d_in[3] = num_graphs (==64, hardcoded as GNUM)
    const float* W     = (const float*)d_in[4];
    const float* b     = (const float*)d_in[5];
    const float* gamma = (const float*)d_in[6];
    const float* beta  = (const float*)d_in[7];
    const float* W1    = (const float*)d_in[8];
    const float* b1    = (const float*)d_in[9];
    const float* W2    = (const float*)d_in[10];
    const float* b2    = (const float*)d_in[11];

    int N = in_sizes[0] / D;
    int E = in_sizes[1] / 2;
    const int* row = ei;
    const int* col = ei + E;

    // workspace carve (256B aligned)
    char* w = (char*)d_ws;
    auto alloc = [&](size_t bytes) { char* p = w; w += (bytes + 255) & ~(size_t)255; return p; };
    int*   deg     = (int*)alloc((size_t)N * 4);
    float* dinv    = (float*)alloc((size_t)N * 4);
    int*   fillc   = (int*)alloc((size_t)N * 4);
    int*   incl    = (int*)alloc((size_t)N * 4);
    int*   bsum    = (int*)alloc(4096);
    int*   rowptr  = (int*)alloc((size_t)(N + 1) * 4);
    int*   ecol    = (int*)alloc((size_t)E * 4);
    float* ednv    = (float*)alloc((size_t)E * 4);
    float* tx1     = (float*)alloc((size_t)N * D * 4);
    float* tbuf    = (float*)alloc((size_t)N * D * 4);
    float* outbuf  = (float*)alloc((size_t)N * D * 4);
    float* bnstats = (float*)alloc(2 * D * 4);
    float* ss      = (float*)alloc(2 * D * 4);
    float* g       = (float*)alloc((size_t)GNUM * D * 4);

    hipMemsetAsync(deg, 0, (size_t)N * 4, stream);
    hipMemsetAsync(fillc, 0, (size_t)N * 4, stream);
    hipMemsetAsync(bnstats, 0, 2 * D * 4, stream);
    hipMemsetAsync(g, 0, (size_t)GNUM * D * 4, stream);

    int nbE = (E + 255) / 256;
    int nbN = (N + 255) / 256;

    k_deg<<<nbE, 256, 0, stream>>>(row, deg, E);
    k_dinv<<<nbN, 256, 0, stream>>>(deg, dinv, N);
    k_scan1<<<nbN, 256, 0, stream>>>(deg, incl, bsum, N);
    k_scan2<<<1, 512, 0, stream>>>(bsum, nbN);
    k_scan3<<<nbN, 256, 0, stream>>>(incl, bsum, rowptr, N);
    k_fill<<<nbE, 256, 0, stream>>>(row, col, rowptr, fillc, dinv, ecol, ednv, E);

    int nbWave = (N * 64 + 255) / 256;  // wave per node
    const float* cur = x;
    for (int step = 0; step < 5; ++step) {
        k_lhat<<<nbWave, 256, 0, stream>>>(cur, rowptr, ecol, ednv, dinv, tx1, N);
        k_cheb<<<2048, 256, 0, stream>>>(cur, tx1, rowptr, ecol, ednv, dinv, W, b, tbuf, bnstats, N);
        k_bnfin<<<1, 64, 0, stream>>>(bnstats, gamma, beta, ss, 1.f / (float)N);
        k_pool<<<nbWave, 256, 0, stream>>>(tbuf, rowptr, ecol, ss, outbuf, N);
        cur = outbuf;
    }

    int chunk = 32;
    int nwaves = (N + chunk - 1) / chunk;
    int nbG = (nwaves * 64 + 255) / 256;
    k_gpool<<<nbG, 256, 0, stream>>>(outbuf, batch, g, N, chunk);
    k_mlp<<<1, 256, 0, stream>>>(g, W1, b1, W2, b2, (float*)d_out);
}

// Round 2
// 1966.828 us; speedup vs baseline: 1.8199x; 1.8199x over previous
//
#include <hip/hip_runtime.h>
#include <hip/hip_bf16.h>

#define D 48
#define GNUM 64
#define HDIM 128
#define ODIM 12
#define BN_EPS 1e-5f

typedef _Float16 half4v __attribute__((ext_vector_type(4)));

// ---------------- setup kernels ----------------

__global__ __launch_bounds__(256) void k_deg(const int* __restrict__ row, int* __restrict__ deg, int E) {
    int e = blockIdx.x * 256 + threadIdx.x;
    if (e < E) atomicAdd(&deg[row[e]], 1);
}

__global__ __launch_bounds__(256) void k_dinv(const int* __restrict__ deg, float* __restrict__ dinv, int N) {
    int i = blockIdx.x * 256 + threadIdx.x;
    if (i < N) dinv[i] = deg[i] > 0 ? rsqrtf((float)deg[i]) : 0.f;
}

__global__ __launch_bounds__(256) void k_scan1(const int* __restrict__ deg, int* __restrict__ incl,
                                               int* __restrict__ bsum, int N) {
    __shared__ int s[256];
    int i = blockIdx.x * 256 + threadIdx.x;
    s[threadIdx.x] = (i < N) ? deg[i] : 0;
    __syncthreads();
    for (int off = 1; off < 256; off <<= 1) {
        int t = (threadIdx.x >= off) ? s[threadIdx.x - off] : 0;
        __syncthreads();
        s[threadIdx.x] += t;
        __syncthreads();
    }
    if (i < N) incl[i] = s[threadIdx.x];
    if (threadIdx.x == 255) bsum[blockIdx.x] = s[255];
}

__global__ __launch_bounds__(512) void k_scan2(int* __restrict__ bsum, int nb) {
    __shared__ int s[512];
    int t = threadIdx.x;
    s[t] = (t < nb) ? bsum[t] : 0;
    __syncthreads();
    for (int off = 1; off < 512; off <<= 1) {
        int v = (t >= off) ? s[t - off] : 0;
        __syncthreads();
        s[t] += v;
        __syncthreads();
    }
    if (t < nb) bsum[t] = s[t];
}

__global__ __launch_bounds__(256) void k_scan3(const int* __restrict__ incl, const int* __restrict__ bsum,
                                               int* __restrict__ rowptr, int N) {
    int i = blockIdx.x * 256 + threadIdx.x;
    if (i < N) {
        int add = (blockIdx.x > 0) ? bsum[blockIdx.x - 1] : 0;
        rowptr[i + 1] = incl[i] + add;
    }
    if (i == 0) rowptr[0] = 0;
}

__global__ __launch_bounds__(256) void k_fill(const int* __restrict__ row, const int* __restrict__ col,
                                              const int* __restrict__ rowptr, int* __restrict__ fillc,
                                              const float* __restrict__ dinv, int2* __restrict__ epair, int E) {
    int e = blockIdx.x * 256 + threadIdx.x;
    if (e < E) {
        int r = row[e], c = col[e];
        int p = rowptr[r] + atomicAdd(&fillc[r], 1);
        epair[p] = make_int2(c, __float_as_int(dinv[c]));
    }
}

__global__ __launch_bounds__(256) void k_cvt(const float* __restrict__ x, _Float16* __restrict__ xh, int n4) {
    int i = blockIdx.x * 256 + threadIdx.x;
    if (i < n4) {
        float4 v = ((const float4*)x)[i];
        half4v h;
        h.x = (_Float16)v.x; h.y = (_Float16)v.y; h.z = (_Float16)v.z; h.w = (_Float16)v.w;
        ((half4v*)xh)[i] = h;
    }
}

// ---------------- per-step kernels ----------------
// Lane layout: 4 slots x 16 lanes. slot = lane>>4, q = lane&15 (q<12 active).
// Lane (slot,q) covers features 4q..4q+3; slot s processes edges p = start+s, +4, ...

// tx1 = lhat(cur)
__global__ __launch_bounds__(256) void k_lhat(const _Float16* __restrict__ cur, const int* __restrict__ rowptr,
                                              const int2* __restrict__ epair, const float* __restrict__ dinv,
                                              _Float16* __restrict__ tx1, int N) {
    int lane = threadIdx.x & 63;
    int i = (blockIdx.x * 256 + threadIdx.x) >> 6;
    if (i >= N) return;
    int q = lane & 15, slot = lane >> 4;
    int qc = q < 12 ? q : 11;  // lanes 12..15 compute isolated garbage, never used
    int s = rowptr[i], e = rowptr[i + 1];
    float a0 = 0.f, a1 = 0.f, a2 = 0.f, a3 = 0.f;
    for (int p = s + slot; p < e; p += 4) {
        int2 ep = epair[p];
        float w = __int_as_float(ep.y);
        half4v h = *(const half4v*)(cur + (size_t)ep.x * D + qc * 4);
        a0 += w * (float)h.x; a1 += w * (float)h.y; a2 += w * (float)h.z; a3 += w * (float)h.w;
    }
    a0 += __shfl_xor(a0, 16); a1 += __shfl_xor(a1, 16); a2 += __shfl_xor(a2, 16); a3 += __shfl_xor(a3, 16);
    a0 += __shfl_xor(a0, 32); a1 += __shfl_xor(a1, 32); a2 += __shfl_xor(a2, 32); a3 += __shfl_xor(a3, 32);
    if (lane < 12) {
        float sc = -dinv[i];
        half4v o;
        o.x = (_Float16)(sc * a0); o.y = (_Float16)(sc * a1);
        o.z = (_Float16)(sc * a2); o.w = (_Float16)(sc * a3);
        *(half4v*)(tx1 + (size_t)i * D + lane * 4) = o;
    }
}

// Tx2 = 2*lhat(Tx1) - Tx0; t = relu(Tx0@W0 + Tx1@W1 + Tx2@W2 + b); BN stat partials
#define WSTRIDE 52
#define WPLANE (D * WSTRIDE)
__global__ __launch_bounds__(256) void k_cheb(const _Float16* __restrict__ tx0, const _Float16* __restrict__ tx1,
                                              const int* __restrict__ rowptr, const int2* __restrict__ epair,
                                              const float* __restrict__ dinv, const float* __restrict__ W,
                                              const float* __restrict__ b, _Float16* __restrict__ tbuf,
                                              float* __restrict__ bnstats, int N) {
    __shared__ float WL[3 * WPLANE];  // 29952 B, k-stride 52 words (208B, 16B-aligned) breaks slot aliasing
    __shared__ float red[2 * D];
    for (int t = threadIdx.x; t < 3 * D * D; t += 256) {
        int kkw = t / (D * D), rem = t % (D * D), k = rem / D, f = rem % D;
        WL[kkw * WPLANE + k * WSTRIDE + f] = W[t];
    }
    if (threadIdx.x < 2 * D) red[threadIdx.x] = 0.f;
    __syncthreads();

    int lane = threadIdx.x & 63;
    int q = lane & 15, slot = lane >> 4;
    int qc = q < 12 ? q : 11;
    int wid = (blockIdx.x * 256 + threadIdx.x) >> 6;
    int nw = (gridDim.x * 256) >> 6;
    int base = lane & 48;

    float4 bb = *(const float4*)(b + qc * 4);
    float ps0 = 0.f, ps1 = 0.f, ps2 = 0.f, ps3 = 0.f;
    float pq0 = 0.f, pq1 = 0.f, pq2 = 0.f, pq3 = 0.f;

    for (int i = wid; i < N; i += nw) {
        int s = rowptr[i], e = rowptr[i + 1];
        half4v h0 = *(const half4v*)(tx0 + (size_t)i * D + qc * 4);
        half4v h1 = *(const half4v*)(tx1 + (size_t)i * D + qc * 4);
        float t0[4] = {(float)h0.x, (float)h0.y, (float)h0.z, (float)h0.w};
        float t1[4] = {(float)h1.x, (float)h1.y, (float)h1.z, (float)h1.w};
        float a0 = 0.f, a1 = 0.f, a2 = 0.f, a3 = 0.f;
        for (int p = s + slot; p < e; p += 4) {
            int2 ep = epair[p];
            float w = __int_as_float(ep.y);
            half4v h = *(const half4v*)(tx1 + (size_t)ep.x * D + qc * 4);
            a0 += w * (float)h.x; a1 += w * (float)h.y; a2 += w * (float)h.z; a3 += w * (float)h.w;
        }
        a0 += __shfl_xor(a0, 16); a1 += __shfl_xor(a1, 16); a2 += __shfl_xor(a2, 16); a3 += __shfl_xor(a3, 16);
        a0 += __shfl_xor(a0, 32); a1 += __shfl_xor(a1, 32); a2 += __shfl_xor(a2, 32); a3 += __shfl_xor(a3, 32);
        float m2di = -2.f * dinv[i];
        float t2[4] = {m2di * a0 - t0[0], m2di * a1 - t0[1], m2di * a2 - t0[2], m2di * a3 - t0[3]};

        // matvec: slot handles k in [12*slot, 12*slot+12)
        float o0 = 0.f, o1 = 0.f, o2 = 0.f, o3 = 0.f;
        int kbase = 12 * slot;
#pragma unroll
        for (int kk = 0; kk < 12; ++kk) {
            const int j = kk & 3;                 // uniform register index
            int src = base + 3 * slot + (kk >> 2);  // lane holding t[k], within own slot group
            float v0 = __shfl(t0[j], src);
            float v1 = __shfl(t1[j], src);
            float v2 = __shfl(t2[j], src);
            const float* wp = &WL[(kbase + kk) * WSTRIDE + qc * 4];
            o0 += v0 * wp[0] + v1 * wp[WPLANE + 0] + v2 * wp[2 * WPLANE + 0];
            o1 += v0 * wp[1] + v1 * wp[WPLANE + 1] + v2 * wp[2 * WPLANE + 1];
            o2 += v0 * wp[2] + v1 * wp[WPLANE + 2] + v2 * wp[2 * WPLANE + 2];
            o3 += v0 * wp[3] + v1 * wp[WPLANE + 3] + v2 * wp[2 * WPLANE + 3];
        }
        o0 += __shfl_xor(o0, 16); o1 += __shfl_xor(o1, 16); o2 += __shfl_xor(o2, 16); o3 += __shfl_xor(o3, 16);
        o0 += __shfl_xor(o0, 32); o1 += __shfl_xor(o1, 32); o2 += __shfl_xor(o2, 32); o3 += __shfl_xor(o3, 32);
        if (lane < 12) {
            o0 = fmaxf(o0 + bb.x, 0.f); o1 = fmaxf(o1 + bb.y, 0.f);
            o2 = fmaxf(o2 + bb.z, 0.f); o3 = fmaxf(o3 + bb.w, 0.f);
            half4v ho;
            ho.x = (_Float16)o0; ho.y = (_Float16)o1; ho.z = (_Float16)o2; ho.w = (_Float16)o3;
            *(half4v*)(tbuf + (size_t)i * D + lane * 4) = ho;
            ps0 += o0; ps1 += o1; ps2 += o2; ps3 += o3;
            pq0 += o0 * o0; pq1 += o1 * o1; pq2 += o2 * o2; pq3 += o3 * o3;
        }
    }
    if (lane < 12) {
        atomicAdd(&red[lane * 4 + 0], ps0); atomicAdd(&red[lane * 4 + 1], ps1);
        atomicAdd(&red[lane * 4 + 2], ps2); atomicAdd(&red[lane * 4 + 3], ps3);
        atomicAdd(&red[D + lane * 4 + 0], pq0); atomicAdd(&red[D + lane * 4 + 1], pq1);
        atomicAdd(&red[D + lane * 4 + 2], pq2); atomicAdd(&red[D + lane * 4 + 3], pq3);
    }
    __syncthreads();
    if (threadIdx.x < 2 * D) atomicAdd(&bnstats[threadIdx.x], red[threadIdx.x]);
}

__global__ __launch_bounds__(64) void k_bnfin(float* __restrict__ bnstats, const float* __restrict__ gamma,
                                              const float* __restrict__ beta, float* __restrict__ ss, float Ninv) {
    int t = threadIdx.x;
    if (t < D) {
        float mean = bnstats[t] * Ninv;
        float var = bnstats[D + t] * Ninv - mean * mean;
        var = fmaxf(var, 0.f);
        float sc = gamma[t] * rsqrtf(var + BN_EPS);
        ss[t] = sc;
        ss[D + t] = beta[t] - mean * sc;
        bnstats[t] = 0.f;
        bnstats[D + t] = 0.f;
    }
}

// out[i] = deg>0 ? BN(max over neighbors of t) : 0   (min tracked for scale<0 generality)
__global__ __launch_bounds__(256) void k_pool(const _Float16* __restrict__ tbuf, const int* __restrict__ rowptr,
                                              const int2* __restrict__ epair, const float* __restrict__ ss,
                                              _Float16* __restrict__ outh, int N) {
    int lane = threadIdx.x & 63;
    int i = (blockIdx.x * 256 + threadIdx.x) >> 6;
    if (i >= N) return;
    int q = lane & 15, slot = lane >> 4;
    int qc = q < 12 ? q : 11;
    int s = rowptr[i], e = rowptr[i + 1];
    float m0 = -3.4e38f, m1 = -3.4e38f, m2 = -3.4e38f, m3 = -3.4e38f;
    float n0 = 3.4e38f, n1 = 3.4e38f, n2 = 3.4e38f, n3 = 3.4e38f;
    for (int p = s + slot; p < e; p += 4) {
        int c = epair[p].x;
        half4v h = *(const half4v*)(tbuf + (size_t)c * D + qc * 4);
        float f0 = (float)h.x, f1 = (float)h.y, f2 = (float)h.z, f3 = (float)h.w;
        m0 = fmaxf(m0, f0); m1 = fmaxf(m1, f1); m2 = fmaxf(m2, f2); m3 = fmaxf(m3, f3);
        n0 = fminf(n0, f0); n1 = fminf(n1, f1); n2 = fminf(n2, f2); n3 = fminf(n3, f3);
    }
    m0 = fmaxf(m0, __shfl_xor(m0, 16)); m1 = fmaxf(m1, __shfl_xor(m1, 16));
    m2 = fmaxf(m2, __shfl_xor(m2, 16)); m3 = fmaxf(m3, __shfl_xor(m3, 16));
    m0 = fmaxf(m0, __shfl_xor(m0, 32)); m1 = fmaxf(m1, __shfl_xor(m1, 32));
    m2 = fmaxf(m2, __shfl_xor(m2, 32)); m3 = fmaxf(m3, __shfl_xor(m3, 32));
    n0 = fminf(n0, __shfl_xor(n0, 16)); n1 = fminf(n1, __shfl_xor(n1, 16));
    n2 = fminf(n2, __shfl_xor(n2, 16)); n3 = fminf(n3, __shfl_xor(n3, 16));
    n0 = fminf(n0, __shfl_xor(n0, 32)); n1 = fminf(n1, __shfl_xor(n1, 32));
    n2 = fminf(n2, __shfl_xor(n2, 32)); n3 = fminf(n3, __shfl_xor(n3, 32));
    if (lane < 12) {
        float4 sc = *(const float4*)(ss + lane * 4);
        float4 sh = *(const float4*)(ss + D + lane * 4);
        half4v o;
        if (s == e) {
            o.x = (_Float16)0.f; o.y = (_Float16)0.f; o.z = (_Float16)0.f; o.w = (_Float16)0.f;
        } else {
            float v0 = (sc.x >= 0.f) ? sc.x * m0 + sh.x : sc.x * n0 + sh.x;
            float v1 = (sc.y >= 0.f) ? sc.y * m1 + sh.y : sc.y * n1 + sh.y;
            float v2 = (sc.z >= 0.f) ? sc.z * m2 + sh.z : sc.z * n2 + sh.z;
            float v3 = (sc.w >= 0.f) ? sc.w * m3 + sh.w : sc.w * n3 + sh.w;
            o.x = (_Float16)v0; o.y = (_Float16)v1; o.z = (_Float16)v2; o.w = (_Float16)v3;
        }
        *(half4v*)(outh + (size_t)i * D + lane * 4) = o;
    }
}

// ---------------- final pooling + MLP ----------------

__global__ __launch_bounds__(256) void k_gpool(const _Float16* __restrict__ outh, const int* __restrict__ batch,
                                               float* __restrict__ g, int N, int chunk) {
    int lane = threadIdx.x & 63;
    int wid = (blockIdx.x * 256 + threadIdx.x) >> 6;
    int start = wid * chunk;
    if (start >= N || lane >= 12) return;
    int end = start + chunk;
    if (end > N) end = N;
    int curb = batch[start];
    float a0 = 0.f, a1 = 0.f, a2 = 0.f, a3 = 0.f;
    for (int i = start; i < end; ++i) {
        int bi = batch[i];
        if (bi != curb) {
            atomicAdd(&g[curb * D + lane * 4 + 0], a0); atomicAdd(&g[curb * D + lane * 4 + 1], a1);
            atomicAdd(&g[curb * D + lane * 4 + 2], a2); atomicAdd(&g[curb * D + lane * 4 + 3], a3);
            curb = bi; a0 = a1 = a2 = a3 = 0.f;
        }
        half4v h = *(const half4v*)(outh + (size_t)i * D + lane * 4);
        a0 += (float)h.x; a1 += (float)h.y; a2 += (float)h.z; a3 += (float)h.w;
    }
    atomicAdd(&g[curb * D + lane * 4 + 0], a0); atomicAdd(&g[curb * D + lane * 4 + 1], a1);
    atomicAdd(&g[curb * D + lane * 4 + 2], a2); atomicAdd(&g[curb * D + lane * 4 + 3], a3);
}

__global__ __launch_bounds__(256) void k_mlp(const float* __restrict__ g, const float* __restrict__ W1,
                                             const float* __restrict__ b1, const float* __restrict__ W2,
                                             const float* __restrict__ b2, float* __restrict__ out) {
    __shared__ float gL[GNUM * D];
    __shared__ float hL[GNUM * HDIM];
    __shared__ float W1L[D * HDIM];
    int t = threadIdx.x;
    for (int i = t; i < GNUM * D; i += 256) gL[i] = g[i];
    for (int i = t; i < D * HDIM; i += 256) W1L[i] = W1[i];
    __syncthreads();
    for (int i = t; i < GNUM * HDIM; i += 256) {
        int gi = i >> 7, hj = i & 127;
        float a = b1[hj];
        for (int k = 0; k < D; ++k) a += gL[gi * D + k] * W1L[k * HDIM + hj];
        hL[i] = fmaxf(a, 0.f);
    }
    __syncthreads();
    for (int i = t; i < GNUM * ODIM; i += 256) {
        int gi = i / ODIM, oj = i % ODIM;
        float a = b2[oj];
        for (int k = 0; k < HDIM; ++k) a += hL[gi * HDIM + k] * W2[k * ODIM + oj];
        out[i] = a;
    }
}

// ---------------- launch ----------------

extern "C" void kernel_launch(void* const* d_in, const int* in_sizes, int n_in,
                              void* d_out, int out_size, void* d_ws, size_t ws_size,
                              hipStream_t stream) {
    const float* x     = (const float*)d_in[0];
    const int*   ei    = (const int*)d_in[1];
    const int*   batch = (const int*)d_in[2];
    const float* W     = (const float*)d_in[4];
    const float* b     = (const float*)d_in[5];
    const float* gamma = (const float*)d_in[6];
    const float* beta  = (const float*)d_in[7];
    const float* W1    = (const float*)d_in[8];
    const float* b1    = (const float*)d_in[9];
    const float* W2    = (const float*)d_in[10];
    const float* b2    = (const float*)d_in[11];

    int N = in_sizes[0] / D;
    int E = in_sizes[1] / 2;
    const int* row = ei;
    const int* col = ei + E;

    char* w = (char*)d_ws;
    auto alloc = [&](size_t bytes) { char* p = w; w += (bytes + 255) & ~(size_t)255; return p; };
    int*       deg     = (int*)alloc((size_t)N * 4);
    float*     dinv    = (float*)alloc((size_t)N * 4);
    int*       fillc   = (int*)alloc((size_t)N * 4);
    int*       incl    = (int*)alloc((size_t)N * 4);
    int*       bsum    = (int*)alloc(4096);
    int*       rowptr  = (int*)alloc((size_t)(N + 1) * 4);
    int2*      epair   = (int2*)alloc((size_t)E * 8);
    _Float16*  xh      = (_Float16*)alloc((size_t)N * D * 2 + 64);
    _Float16*  tx1h    = (_Float16*)alloc((size_t)N * D * 2 + 64);
    _Float16*  tbufh   = (_Float16*)alloc((size_t)N * D * 2 + 64);
    _Float16*  outh    = (_Float16*)alloc((size_t)N * D * 2 + 64);
    float*     bnstats = (float*)alloc(2 * D * 4);
    float*     ss      = (float*)alloc(2 * D * 4);
    float*     g       = (float*)alloc((size_t)GNUM * D * 4);

    hipMemsetAsync(deg, 0, (size_t)N * 4, stream);
    hipMemsetAsync(fillc, 0, (size_t)N * 4, stream);
    hipMemsetAsync(bnstats, 0, 2 * D * 4, stream);
    hipMemsetAsync(g, 0, (size_t)GNUM * D * 4, stream);

    int nbE = (E + 255) / 256;
    int nbN = (N + 255) / 256;

    k_deg<<<nbE, 256, 0, stream>>>(row, deg, E);
    k_dinv<<<nbN, 256, 0, stream>>>(deg, dinv, N);
    k_scan1<<<nbN, 256, 0, stream>>>(deg, incl, bsum, N);
    k_scan2<<<1, 512, 0, stream>>>(bsum, nbN);
    k_scan3<<<nbN, 256, 0, stream>>>(incl, bsum, rowptr, N);
    k_fill<<<nbE, 256, 0, stream>>>(row, col, rowptr, fillc, dinv, epair, E);
    int n4 = N * D / 4;
    k_cvt<<<(n4 + 255) / 256, 256, 0, stream>>>(x, xh, n4);

    int nbWave = (N * 64 + 255) / 256;
    const _Float16* cur = xh;
    for (int step = 0; step < 5; ++step) {
        k_lhat<<<nbWave, 256, 0, stream>>>(cur, rowptr, epair, dinv, tx1h, N);
        k_cheb<<<2048, 256, 0, stream>>>(cur, tx1h, rowptr, epair, dinv, W, b, tbufh, bnstats, N);
        k_bnfin<<<1, 64, 0, stream>>>(bnstats, gamma, beta, ss, 1.f / (float)N);
        k_pool<<<nbWave, 256, 0, stream>>>(tbufh, rowptr, epair, ss, outh, N);
        cur = outh;
    }

    int chunk = 32;
    int nwaves = (N + chunk - 1) / chunk;
    int nbG = (nwaves * 64 + 255) / 256;
    k_gpool<<<nbG, 256, 0, stream>>>(outh, batch, g, N, chunk);
    k_mlp<<<1, 256, 0, stream>>>(g, W1, b1, W2, b2, (float*)d_out);
}

// Round 3
// 1268.618 us; speedup vs baseline: 2.8215x; 1.5504x over previous
//
#include <hip/hip_runtime.h>
#include <hip/hip_bf16.h>

#define D 48
#define GNUM 64
#define HDIM 128
#define ODIM 12
#define BN_EPS 1e-5f

typedef _Float16 half2v __attribute__((ext_vector_type(2)));
typedef _Float16 half4v __attribute__((ext_vector_type(4)));
typedef _Float16 half8v __attribute__((ext_vector_type(8)));

#if __has_builtin(__builtin_amdgcn_fdot2)
#define FDOT2(a, b, c) __builtin_amdgcn_fdot2((a), (b), (c), false)
#else
#define FDOT2(a, b, c) ((c) + (float)(a)[0] * (float)(b)[0] + (float)(a)[1] * (float)(b)[1])
#endif

// ---------------- setup kernels ----------------

__global__ __launch_bounds__(256) void k_deg(const int* __restrict__ row, int* __restrict__ deg, int E) {
    int e = blockIdx.x * 256 + threadIdx.x;
    if (e < E) atomicAdd(&deg[row[e]], 1);
}

__global__ __launch_bounds__(256) void k_dinv(const int* __restrict__ deg, float* __restrict__ dinv, int N) {
    int i = blockIdx.x * 256 + threadIdx.x;
    if (i < N) dinv[i] = deg[i] > 0 ? rsqrtf((float)deg[i]) : 0.f;
}

__global__ __launch_bounds__(256) void k_scan1(const int* __restrict__ deg, int* __restrict__ incl,
                                               int* __restrict__ bsum, int N) {
    __shared__ int s[256];
    int i = blockIdx.x * 256 + threadIdx.x;
    s[threadIdx.x] = (i < N) ? deg[i] : 0;
    __syncthreads();
    for (int off = 1; off < 256; off <<= 1) {
        int t = (threadIdx.x >= off) ? s[threadIdx.x - off] : 0;
        __syncthreads();
        s[threadIdx.x] += t;
        __syncthreads();
    }
    if (i < N) incl[i] = s[threadIdx.x];
    if (threadIdx.x == 255) bsum[blockIdx.x] = s[255];
}

__global__ __launch_bounds__(512) void k_scan2(int* __restrict__ bsum, int nb) {
    __shared__ int s[512];
    int t = threadIdx.x;
    s[t] = (t < nb) ? bsum[t] : 0;
    __syncthreads();
    for (int off = 1; off < 512; off <<= 1) {
        int v = (t >= off) ? s[t - off] : 0;
        __syncthreads();
        s[t] += v;
        __syncthreads();
    }
    if (t < nb) bsum[t] = s[t];
}

__global__ __launch_bounds__(256) void k_scan3(const int* __restrict__ incl, const int* __restrict__ bsum,
                                               int* __restrict__ rowptr, int N) {
    int i = blockIdx.x * 256 + threadIdx.x;
    if (i < N) {
        int add = (blockIdx.x > 0) ? bsum[blockIdx.x - 1] : 0;
        rowptr[i + 1] = incl[i] + add;
    }
    if (i == 0) rowptr[0] = 0;
}

__global__ __launch_bounds__(256) void k_fill(const int* __restrict__ row, const int* __restrict__ col,
                                              const int* __restrict__ rowptr, int* __restrict__ fillc,
                                              const float* __restrict__ dinv, int2* __restrict__ epair, int E) {
    int e = blockIdx.x * 256 + threadIdx.x;
    if (e < E) {
        int r = row[e], c = col[e];
        int p = rowptr[r] + atomicAdd(&fillc[r], 1);
        epair[p] = make_int2(c, __float_as_int(dinv[c]));
    }
}

__global__ __launch_bounds__(256) void k_cvt(const float* __restrict__ x, _Float16* __restrict__ xh, int n4) {
    int i = blockIdx.x * 256 + threadIdx.x;
    if (i < n4) {
        float4 v = ((const float4*)x)[i];
        half4v h;
        h.x = (_Float16)v.x; h.y = (_Float16)v.y; h.z = (_Float16)v.z; h.w = (_Float16)v.w;
        ((half4v*)xh)[i] = h;
    }
}

// ---------------- gather kernels ----------------
// 4 slots x 16 lanes; q<12 active per slot; p-loop unrolled x2.

__global__ __launch_bounds__(256) void k_lhat(const _Float16* __restrict__ cur, const int* __restrict__ rowptr,
                                              const int2* __restrict__ epair, const float* __restrict__ dinv,
                                              _Float16* __restrict__ tx1, int N) {
    int lane = threadIdx.x & 63;
    int i = (blockIdx.x * 256 + threadIdx.x) >> 6;
    if (i >= N) return;
    int q = lane & 15, slot = lane >> 4;
    int qc = q < 12 ? q : 11;
    int s = rowptr[i], e = rowptr[i + 1];
    float a0 = 0.f, a1 = 0.f, a2 = 0.f, a3 = 0.f;
    int p = s + slot;
    for (; p + 4 < e; p += 8) {
        int2 ea = epair[p];
        int2 eb = epair[p + 4];
        float wa = __int_as_float(ea.y), wb = __int_as_float(eb.y);
        half4v ha = *(const half4v*)(cur + (size_t)ea.x * D + qc * 4);
        half4v hb = *(const half4v*)(cur + (size_t)eb.x * D + qc * 4);
        a0 += wa * (float)ha.x + wb * (float)hb.x;
        a1 += wa * (float)ha.y + wb * (float)hb.y;
        a2 += wa * (float)ha.z + wb * (float)hb.z;
        a3 += wa * (float)ha.w + wb * (float)hb.w;
    }
    if (p < e) {
        int2 ea = epair[p];
        float wa = __int_as_float(ea.y);
        half4v ha = *(const half4v*)(cur + (size_t)ea.x * D + qc * 4);
        a0 += wa * (float)ha.x; a1 += wa * (float)ha.y; a2 += wa * (float)ha.z; a3 += wa * (float)ha.w;
    }
    a0 += __shfl_xor(a0, 16); a1 += __shfl_xor(a1, 16); a2 += __shfl_xor(a2, 16); a3 += __shfl_xor(a3, 16);
    a0 += __shfl_xor(a0, 32); a1 += __shfl_xor(a1, 32); a2 += __shfl_xor(a2, 32); a3 += __shfl_xor(a3, 32);
    if (lane < 12) {
        float sc = -dinv[i];
        half4v o;
        o.x = (_Float16)(sc * a0); o.y = (_Float16)(sc * a1);
        o.z = (_Float16)(sc * a2); o.w = (_Float16)(sc * a3);
        *(half4v*)(tx1 + (size_t)i * D + lane * 4) = o;
    }
}

__global__ __launch_bounds__(256) void k_gather2(const _Float16* __restrict__ tx0, const _Float16* __restrict__ tx1,
                                                 const int* __restrict__ rowptr, const int2* __restrict__ epair,
                                                 const float* __restrict__ dinv, _Float16* __restrict__ tx2, int N) {
    int lane = threadIdx.x & 63;
    int i = (blockIdx.x * 256 + threadIdx.x) >> 6;
    if (i >= N) return;
    int q = lane & 15, slot = lane >> 4;
    int qc = q < 12 ? q : 11;
    int s = rowptr[i], e = rowptr[i + 1];
    float a0 = 0.f, a1 = 0.f, a2 = 0.f, a3 = 0.f;
    int p = s + slot;
    for (; p + 4 < e; p += 8) {
        int2 ea = epair[p];
        int2 eb = epair[p + 4];
        float wa = __int_as_float(ea.y), wb = __int_as_float(eb.y);
        half4v ha = *(const half4v*)(tx1 + (size_t)ea.x * D + qc * 4);
        half4v hb = *(const half4v*)(tx1 + (size_t)eb.x * D + qc * 4);
        a0 += wa * (float)ha.x + wb * (float)hb.x;
        a1 += wa * (float)ha.y + wb * (float)hb.y;
        a2 += wa * (float)ha.z + wb * (float)hb.z;
        a3 += wa * (float)ha.w + wb * (float)hb.w;
    }
    if (p < e) {
        int2 ea = epair[p];
        float wa = __int_as_float(ea.y);
        half4v ha = *(const half4v*)(tx1 + (size_t)ea.x * D + qc * 4);
        a0 += wa * (float)ha.x; a1 += wa * (float)ha.y; a2 += wa * (float)ha.z; a3 += wa * (float)ha.w;
    }
    a0 += __shfl_xor(a0, 16); a1 += __shfl_xor(a1, 16); a2 += __shfl_xor(a2, 16); a3 += __shfl_xor(a3, 16);
    a0 += __shfl_xor(a0, 32); a1 += __shfl_xor(a1, 32); a2 += __shfl_xor(a2, 32); a3 += __shfl_xor(a3, 32);
    if (lane < 12) {
        float sc = -2.f * dinv[i];
        half4v h0 = *(const half4v*)(tx0 + (size_t)i * D + lane * 4);
        half4v o;
        o.x = (_Float16)(sc * a0 - (float)h0.x); o.y = (_Float16)(sc * a1 - (float)h0.y);
        o.z = (_Float16)(sc * a2 - (float)h0.z); o.w = (_Float16)(sc * a3 - (float)h0.w);
        *(half4v*)(tx2 + (size_t)i * D + lane * 4) = o;
    }
}

// ---------------- dense: t = relu([tx0|tx1|tx2] @ W + b) ----------------

__global__ __launch_bounds__(256) void k_dense(const _Float16* __restrict__ tx0, const _Float16* __restrict__ tx1,
                                               const _Float16* __restrict__ tx2, const float* __restrict__ W,
                                               const float* __restrict__ b, _Float16* __restrict__ tbuf, int N) {
    __shared__ half2v WH2[72 * D];  // [kp][j] = (W[2kp][j], W[2kp+1][j]); 13824 B
    __shared__ float bL[D];
    for (int t = threadIdx.x; t < 72 * D; t += 256) {
        int kp = t / D, j = t % D;
        half2v w;
        w.x = (_Float16)W[(2 * kp) * D + j];
        w.y = (_Float16)W[(2 * kp + 1) * D + j];
        WH2[t] = w;
    }
    if (threadIdx.x < D) bL[threadIdx.x] = b[threadIdx.x];
    __syncthreads();

    int base = (blockIdx.x * 256 + threadIdx.x) * 2;
    if (base >= N) return;
    bool two = (base + 1) < N;

    const _Float16* rowsA[3] = {tx0 + (size_t)base * D, tx1 + (size_t)base * D, tx2 + (size_t)base * D};
    size_t off2 = two ? D : 0;

    float acc0[D], acc1[D];
#pragma unroll
    for (int j = 0; j < D; ++j) { acc0[j] = bL[j]; acc1[j] = bL[j]; }

    for (int s = 0; s < 3; ++s) {
        const half2v* xa = (const half2v*)rowsA[s];
        const half2v* xb = (const half2v*)(rowsA[s] + off2);
#pragma unroll 4
        for (int g = 0; g < 24; ++g) {
            half2v va = xa[g], vb = xb[g];
            int kp = s * 24 + g;
            const half8v* wr = (const half8v*)&WH2[kp * D];
#pragma unroll
            for (int jc = 0; jc < 12; ++jc) {
                half8v w = wr[jc];
                half2v w0; w0.x = w[0]; w0.y = w[1];
                half2v w1; w1.x = w[2]; w1.y = w[3];
                half2v w2; w2.x = w[4]; w2.y = w[5];
                half2v w3; w3.x = w[6]; w3.y = w[7];
                acc0[jc * 4 + 0] = FDOT2(va, w0, acc0[jc * 4 + 0]);
                acc0[jc * 4 + 1] = FDOT2(va, w1, acc0[jc * 4 + 1]);
                acc0[jc * 4 + 2] = FDOT2(va, w2, acc0[jc * 4 + 2]);
                acc0[jc * 4 + 3] = FDOT2(va, w3, acc0[jc * 4 + 3]);
                acc1[jc * 4 + 0] = FDOT2(vb, w0, acc1[jc * 4 + 0]);
                acc1[jc * 4 + 1] = FDOT2(vb, w1, acc1[jc * 4 + 1]);
                acc1[jc * 4 + 2] = FDOT2(vb, w2, acc1[jc * 4 + 2]);
                acc1[jc * 4 + 3] = FDOT2(vb, w3, acc1[jc * 4 + 3]);
            }
        }
    }

    _Float16* o0 = tbuf + (size_t)base * D;
#pragma unroll
    for (int jc = 0; jc < 12; ++jc) {
        half4v h;
        h.x = (_Float16)fmaxf(acc0[jc * 4 + 0], 0.f);
        h.y = (_Float16)fmaxf(acc0[jc * 4 + 1], 0.f);
        h.z = (_Float16)fmaxf(acc0[jc * 4 + 2], 0.f);
        h.w = (_Float16)fmaxf(acc0[jc * 4 + 3], 0.f);
        *(half4v*)(o0 + jc * 4) = h;
    }
    if (two) {
        _Float16* o1 = o0 + D;
#pragma unroll
        for (int jc = 0; jc < 12; ++jc) {
            half4v h;
            h.x = (_Float16)fmaxf(acc1[jc * 4 + 0], 0.f);
            h.y = (_Float16)fmaxf(acc1[jc * 4 + 1], 0.f);
            h.z = (_Float16)fmaxf(acc1[jc * 4 + 2], 0.f);
            h.w = (_Float16)fmaxf(acc1[jc * 4 + 3], 0.f);
            *(half4v*)(o1 + jc * 4) = h;
        }
    }
}

// ---------------- BN stats / finalize ----------------

__global__ __launch_bounds__(256) void k_bnstat(const _Float16* __restrict__ tbuf, float* __restrict__ bnstats, int N) {
    __shared__ float red[2 * D];
    if (threadIdx.x < 2 * D) red[threadIdx.x] = 0.f;
    __syncthreads();
    int tid = blockIdx.x * 256 + threadIdx.x;
    int q = tid % 12;
    int n0 = tid / 12;
    int stride = (gridDim.x * 256) / 12;
    float s0 = 0, s1 = 0, s2 = 0, s3 = 0, q0 = 0, q1 = 0, q2 = 0, q3 = 0;
    for (int n = n0; n < N; n += stride) {
        half4v h = *(const half4v*)(tbuf + (size_t)n * D + q * 4);
        float f0 = (float)h.x, f1 = (float)h.y, f2 = (float)h.z, f3 = (float)h.w;
        s0 += f0; s1 += f1; s2 += f2; s3 += f3;
        q0 += f0 * f0; q1 += f1 * f1; q2 += f2 * f2; q3 += f3 * f3;
    }
    atomicAdd(&red[q * 4 + 0], s0); atomicAdd(&red[q * 4 + 1], s1);
    atomicAdd(&red[q * 4 + 2], s2); atomicAdd(&red[q * 4 + 3], s3);
    atomicAdd(&red[D + q * 4 + 0], q0); atomicAdd(&red[D + q * 4 + 1], q1);
    atomicAdd(&red[D + q * 4 + 2], q2); atomicAdd(&red[D + q * 4 + 3], q3);
    __syncthreads();
    if (threadIdx.x < 2 * D) atomicAdd(&bnstats[threadIdx.x], red[threadIdx.x]);
}

__global__ __launch_bounds__(64) void k_bnfin(float* __restrict__ bnstats, const float* __restrict__ gamma,
                                              const float* __restrict__ beta, float* __restrict__ ss, float Ninv) {
    int t = threadIdx.x;
    if (t < D) {
        float mean = bnstats[t] * Ninv;
        float var = bnstats[D + t] * Ninv - mean * mean;
        var = fmaxf(var, 0.f);
        float sc = gamma[t] * rsqrtf(var + BN_EPS);
        ss[t] = sc;
        ss[D + t] = beta[t] - mean * sc;
        bnstats[t] = 0.f;
        bnstats[D + t] = 0.f;
    }
}

// ---------------- pool ----------------

__global__ __launch_bounds__(256) void k_pool(const _Float16* __restrict__ tbuf, const int* __restrict__ rowptr,
                                              const int2* __restrict__ epair, const float* __restrict__ ss,
                                              _Float16* __restrict__ outh, int N) {
    int lane = threadIdx.x & 63;
    int i = (blockIdx.x * 256 + threadIdx.x) >> 6;
    if (i >= N) return;
    int q = lane & 15, slot = lane >> 4;
    int qc = q < 12 ? q : 11;
    int s = rowptr[i], e = rowptr[i + 1];
    float m0 = -3.4e38f, m1 = -3.4e38f, m2 = -3.4e38f, m3 = -3.4e38f;
    float n0 = 3.4e38f, n1 = 3.4e38f, n2 = 3.4e38f, n3 = 3.4e38f;
    int p = s + slot;
    for (; p + 4 < e; p += 8) {
        int ca = epair[p].x, cb = epair[p + 4].x;
        half4v ha = *(const half4v*)(tbuf + (size_t)ca * D + qc * 4);
        half4v hb = *(const half4v*)(tbuf + (size_t)cb * D + qc * 4);
        float a0 = (float)ha.x, a1 = (float)ha.y, a2 = (float)ha.z, a3 = (float)ha.w;
        float b0 = (float)hb.x, b1 = (float)hb.y, b2 = (float)hb.z, b3 = (float)hb.w;
        m0 = fmaxf(m0, fmaxf(a0, b0)); m1 = fmaxf(m1, fmaxf(a1, b1));
        m2 = fmaxf(m2, fmaxf(a2, b2)); m3 = fmaxf(m3, fmaxf(a3, b3));
        n0 = fminf(n0, fminf(a0, b0)); n1 = fminf(n1, fminf(a1, b1));
        n2 = fminf(n2, fminf(a2, b2)); n3 = fminf(n3, fminf(a3, b3));
    }
    if (p < e) {
        int ca = epair[p].x;
        half4v ha = *(const half4v*)(tbuf + (size_t)ca * D + qc * 4);
        float a0 = (float)ha.x, a1 = (float)ha.y, a2 = (float)ha.z, a3 = (float)ha.w;
        m0 = fmaxf(m0, a0); m1 = fmaxf(m1, a1); m2 = fmaxf(m2, a2); m3 = fmaxf(m3, a3);
        n0 = fminf(n0, a0); n1 = fminf(n1, a1); n2 = fminf(n2, a2); n3 = fminf(n3, a3);
    }
    m0 = fmaxf(m0, __shfl_xor(m0, 16)); m1 = fmaxf(m1, __shfl_xor(m1, 16));
    m2 = fmaxf(m2, __shfl_xor(m2, 16)); m3 = fmaxf(m3, __shfl_xor(m3, 16));
    m0 = fmaxf(m0, __shfl_xor(m0, 32)); m1 = fmaxf(m1, __shfl_xor(m1, 32));
    m2 = fmaxf(m2, __shfl_xor(m2, 32)); m3 = fmaxf(m3, __shfl_xor(m3, 32));
    n0 = fminf(n0, __shfl_xor(n0, 16)); n1 = fminf(n1, __shfl_xor(n1, 16));
    n2 = fminf(n2, __shfl_xor(n2, 16)); n3 = fminf(n3, __shfl_xor(n3, 16));
    n0 = fminf(n0, __shfl_xor(n0, 32)); n1 = fminf(n1, __shfl_xor(n1, 32));
    n2 = fminf(n2, __shfl_xor(n2, 32)); n3 = fminf(n3, __shfl_xor(n3, 32));
    if (lane < 12) {
        float4 sc = *(const float4*)(ss + lane * 4);
        float4 sh = *(const float4*)(ss + D + lane * 4);
        half4v o;
        if (s == e) {
            o.x = (_Float16)0.f; o.y = (_Float16)0.f; o.z = (_Float16)0.f; o.w = (_Float16)0.f;
        } else {
            float v0 = (sc.x >= 0.f) ? sc.x * m0 + sh.x : sc.x * n0 + sh.x;
            float v1 = (sc.y >= 0.f) ? sc.y * m1 + sh.y : sc.y * n1 + sh.y;
            float v2 = (sc.z >= 0.f) ? sc.z * m2 + sh.z : sc.z * n2 + sh.z;
            float v3 = (sc.w >= 0.f) ? sc.w * m3 + sh.w : sc.w * n3 + sh.w;
            o.x = (_Float16)v0; o.y = (_Float16)v1; o.z = (_Float16)v2; o.w = (_Float16)v3;
        }
        *(half4v*)(outh + (size_t)i * D + lane * 4) = o;
    }
}

// ---------------- final pooling + MLP ----------------

__global__ __launch_bounds__(256) void k_gpool(const _Float16* __restrict__ outh, const int* __restrict__ batch,
                                               float* __restrict__ g, int N, int chunk) {
    int lane = threadIdx.x & 63;
    int wid = (blockIdx.x * 256 + threadIdx.x) >> 6;
    int start = wid * chunk;
    if (start >= N || lane >= 12) return;
    int end = start + chunk;
    if (end > N) end = N;
    int curb = batch[start];
    float a0 = 0.f, a1 = 0.f, a2 = 0.f, a3 = 0.f;
    for (int i = start; i < end; ++i) {
        int bi = batch[i];
        if (bi != curb) {
            atomicAdd(&g[curb * D + lane * 4 + 0], a0); atomicAdd(&g[curb * D + lane * 4 + 1], a1);
            atomicAdd(&g[curb * D + lane * 4 + 2], a2); atomicAdd(&g[curb * D + lane * 4 + 3], a3);
            curb = bi; a0 = a1 = a2 = a3 = 0.f;
        }
        half4v h = *(const half4v*)(outh + (size_t)i * D + lane * 4);
        a0 += (float)h.x; a1 += (float)h.y; a2 += (float)h.z; a3 += (float)h.w;
    }
    atomicAdd(&g[curb * D + lane * 4 + 0], a0); atomicAdd(&g[curb * D + lane * 4 + 1], a1);
    atomicAdd(&g[curb * D + lane * 4 + 2], a2); atomicAdd(&g[curb * D + lane * 4 + 3], a3);
}

__global__ __launch_bounds__(256) void k_mlp(const float* __restrict__ g, const float* __restrict__ W1,
                                             const float* __restrict__ b1, const float* __restrict__ W2,
                                             const float* __restrict__ b2, float* __restrict__ out) {
    __shared__ float gL[GNUM * D];
    __shared__ float hL[GNUM * HDIM];
    __shared__ float W1L[D * HDIM];
    int t = threadIdx.x;
    for (int i = t; i < GNUM * D; i += 256) gL[i] = g[i];
    for (int i = t; i < D * HDIM; i += 256) W1L[i] = W1[i];
    __syncthreads();
    for (int i = t; i < GNUM * HDIM; i += 256) {
        int gi = i >> 7, hj = i & 127;
        float a = b1[hj];
        for (int k = 0; k < D; ++k) a += gL[gi * D + k] * W1L[k * HDIM + hj];
        hL[i] = fmaxf(a, 0.f);
    }
    __syncthreads();
    for (int i = t; i < GNUM * ODIM; i += 256) {
        int gi = i / ODIM, oj = i % ODIM;
        float a = b2[oj];
        for (int k = 0; k < HDIM; ++k) a += hL[gi * HDIM + k] * W2[k * ODIM + oj];
        out[i] = a;
    }
}

// ---------------- launch ----------------

extern "C" void kernel_launch(void* const* d_in, const int* in_sizes, int n_in,
                              void* d_out, int out_size, void* d_ws, size_t ws_size,
                              hipStream_t stream) {
    const float* x     = (const float*)d_in[0];
    const int*   ei    = (const int*)d_in[1];
    const int*   batch = (const int*)d_in[2];
    const float* W     = (const float*)d_in[4];
    const float* b     = (const float*)d_in[5];
    const float* gamma = (const float*)d_in[6];
    const float* beta  = (const float*)d_in[7];
    const float* W1    = (const float*)d_in[8];
    const float* b1    = (const float*)d_in[9];
    const float* W2    = (const float*)d_in[10];
    const float* b2    = (const float*)d_in[11];

    int N = in_sizes[0] / D;
    int E = in_sizes[1] / 2;
    const int* row = ei;
    const int* col = ei + E;

    char* w = (char*)d_ws;
    auto alloc = [&](size_t bytes) { char* p = w; w += (bytes + 255) & ~(size_t)255; return p; };
    int*       deg     = (int*)alloc((size_t)N * 4);
    float*     dinv    = (float*)alloc((size_t)N * 4);
    int*       fillc   = (int*)alloc((size_t)N * 4);
    int*       incl    = (int*)alloc((size_t)N * 4);
    int*       bsum    = (int*)alloc(4096);
    int*       rowptr  = (int*)alloc((size_t)(N + 1) * 4);
    int2*      epair   = (int2*)alloc((size_t)E * 8);
    _Float16*  xh      = (_Float16*)alloc((size_t)N * D * 2 + 64);
    _Float16*  tx1h    = (_Float16*)alloc((size_t)N * D * 2 + 64);
    _Float16*  tx2h    = (_Float16*)alloc((size_t)N * D * 2 + 64);
    _Float16*  tbufh   = (_Float16*)alloc((size_t)N * D * 2 + 64);
    _Float16*  outh    = (_Float16*)alloc((size_t)N * D * 2 + 64);
    float*     bnstats = (float*)alloc(2 * D * 4);
    float*     ss      = (float*)alloc(2 * D * 4);
    float*     g       = (float*)alloc((size_t)GNUM * D * 4);

    hipMemsetAsync(deg, 0, (size_t)N * 4, stream);
    hipMemsetAsync(fillc, 0, (size_t)N * 4, stream);
    hipMemsetAsync(bnstats, 0, 2 * D * 4, stream);
    hipMemsetAsync(g, 0, (size_t)GNUM * D * 4, stream);

    int nbE = (E + 255) / 256;
    int nbN = (N + 255) / 256;

    k_deg<<<nbE, 256, 0, stream>>>(row, deg, E);
    k_dinv<<<nbN, 256, 0, stream>>>(deg, dinv, N);
    k_scan1<<<nbN, 256, 0, stream>>>(deg, incl, bsum, N);
    k_scan2<<<1, 512, 0, stream>>>(bsum, nbN);
    k_scan3<<<nbN, 256, 0, stream>>>(incl, bsum, rowptr, N);
    k_fill<<<nbE, 256, 0, stream>>>(row, col, rowptr, fillc, dinv, epair, E);
    int n4 = N * D / 4;
    k_cvt<<<(n4 + 255) / 256, 256, 0, stream>>>(x, xh, n4);

    int nbWave = (N * 64 + 255) / 256;
    int nbDense = ((N + 1) / 2 + 255) / 256;
    const _Float16* cur = xh;
    for (int step = 0; step < 5; ++step) {
        k_lhat<<<nbWave, 256, 0, stream>>>(cur, rowptr, epair, dinv, tx1h, N);
        k_gather2<<<nbWave, 256, 0, stream>>>(cur, tx1h, rowptr, epair, dinv, tx2h, N);
        k_dense<<<nbDense, 256, 0, stream>>>(cur, tx1h, tx2h, W, b, tbufh, N);
        k_bnstat<<<120, 256, 0, stream>>>(tbufh, bnstats, N);
        k_bnfin<<<1, 64, 0, stream>>>(bnstats, gamma, beta, ss, 1.f / (float)N);
        k_pool<<<nbWave, 256, 0, stream>>>(tbufh, rowptr, epair, ss, outh, N);
        cur = outh;
    }

    int chunk = 32;
    int nwaves = (N + chunk - 1) / chunk;
    int nbG = (nwaves * 64 + 255) / 256;
    k_gpool<<<nbG, 256, 0, stream>>>(outh, batch, g, N, chunk);
    k_mlp<<<1, 256, 0, stream>>>(g, W1, b1, W2, b2, (float*)d_out);
}